// Round 2
// baseline (872.779 us; speedup 1.0000x reference)
//
#include <hip/hip_runtime.h>
#include <hip/hip_bf16.h>
#include <stdint.h>

#define LATF 256
#define NT 119
#define NNODES 100000
#define NEDGES 400000

typedef __attribute__((ext_vector_type(8))) short short8;
typedef __attribute__((ext_vector_type(4))) float f4;

__device__ __forceinline__ float bf2f(short u) {
  union { uint32_t i; float f; } v; v.i = ((uint32_t)(uint16_t)u) << 16; return v.f;
}
__device__ __forceinline__ short f2bf(float f) {
  union { float f; uint32_t i; } v; v.f = f;
  uint32_t r = (v.i + 0x7fffu + ((v.i >> 16) & 1u)) >> 16;
  return (short)(uint16_t)r;
}

// ---------------- prep: cast + build transposed weight layouts ----------------
__global__ __launch_bounds__(256) void prep_kernel(
    const float* __restrict__ lat, const float* __restrict__ pos,
    const float* __restrict__ nW1, const float* __restrict__ tW1, const float* __restrict__ dW1,
    const float* __restrict__ nW2, const float* __restrict__ tW2, const float* __restrict__ dW2,
    const float* __restrict__ nW3, const float* __restrict__ tW3, const float* __restrict__ dW3,
    short* __restrict__ latent_bf, short* __restrict__ pos_bf,
    short* __restrict__ Wtcat, short* __restrict__ Wt2cat,
    short* __restrict__ Wt3n, short* __restrict__ Wt3t, short* __restrict__ Wt3d)
{
  int i = blockIdx.x * 256 + threadIdx.x;
  if (i < 524288) { latent_bf[i] = f2bf(lat[i]); return; }
  i -= 524288;
  if (i < 800000) { pos_bf[i] = f2bf(pos[i]); return; }
  i -= 800000;
  if (i < 1280 * 288) {               // Wtcat[n][k], n-major, K padded 264->288
    int n = i / 288, k = i % 288;
    float v = 0.f;
    if (k < 264) {
      if (n < 256)       v = nW1[k * 256 + n];
      else if (n < 512)  v = tW1[k * 256 + (n - 256)];
      else if (n < 768)  v = tW1[(264 + k) * 256 + (n - 512)];
      else if (n < 1024) v = dW1[k * 256 + (n - 768)];
      else               v = dW1[(264 + k) * 256 + (n - 1024)];
    }
    Wtcat[n * 288 + k] = f2bf(v);
    return;
  }
  i -= 1280 * 288;
  if (i < 384 * 256) {                // Wt2cat[n][k]: rows 0-127 nW2, 128-255 tW2, 256-383 dW2
    int n = i / 256, k = i % 256;
    float v = (n < 128) ? nW2[k * 128 + n] : (n < 256) ? tW2[k * 128 + (n - 128)]
                                                       : dW2[k * 128 + (n - 256)];
    Wt2cat[n * 256 + k] = f2bf(v);
    return;
  }
  i -= 384 * 256;
  if (i < 128 * 128) {                // Wt3n[n][k], n padded 119->128
    int n = i / 128, k = i % 128;
    Wt3n[i] = (n < NT) ? f2bf(nW3[k * NT + n]) : (short)0;
    return;
  }
  i -= 128 * 128;
  if (i < 4 * 128) { int n = i / 128, k = i % 128; Wt3t[i] = f2bf(tW3[k * 4 + n]); return; }
  i -= 512;
  if (i < 3 * 128) { int n = i / 128, k = i % 128; Wt3d[i] = f2bf(dW3[k * 3 + n]); return; }
}

// ---------------- K1: nodeFeat x [nW1 | tW1_src | tW1_dst | dW1_src | dW1_dst] ----------------
// M=100000, K=288 (pad), N=1280. BM=64, BN=128, 4 waves (2x2), each wave 32x64.
// Epilogue folds tb1 (Pall cols 0:256) and db1 (cols 512:768) into the src projections.
__global__ __launch_bounds__(256) void k1_gemm(
    const short* __restrict__ latent_bf, const short* __restrict__ pos_bf,
    const int* __restrict__ batch, const short* __restrict__ Wtcat,
    const float* __restrict__ nb1, const float* __restrict__ tb1, const float* __restrict__ db1,
    short* __restrict__ h1_node, short* __restrict__ Pall)
{
  __shared__ short As[64 * 40];   // 32 K-elems + pad 8 -> row stride 80B (2-way max)
  const int t = threadIdx.x;
  const int bm0 = blockIdx.x * 64;
  const int n0 = blockIdx.y * 128;
  const int wid = t >> 6, lane = t & 63;
  const int wm = wid >> 1, wn = wid & 1;
  const int lrow = lane & 15, kq = lane >> 4;

  const int sr = t >> 2, sq = t & 3;          // staging: 4 threads per row
  const int m_stage = bm0 + sr;
  const bool svalid = (m_stage < NNODES);
  const int g = svalid ? batch[m_stage] : 0;

  f4 acc[2][4];
  #pragma unroll
  for (int a = 0; a < 2; ++a)
    #pragma unroll
    for (int b = 0; b < 4; ++b) acc[a][b] = (f4){0.f, 0.f, 0.f, 0.f};

  for (int kc = 0; kc < 9; ++kc) {
    const int k0 = kc * 32;
    short8 av = {0, 0, 0, 0, 0, 0, 0, 0};
    if (svalid) {
      if (k0 < 256)      av = *(const short8*)(latent_bf + g * 256 + k0 + sq * 8);
      else if (sq == 0)  av = *(const short8*)(pos_bf + m_stage * 8);
    }
    *(short8*)(As + sr * 40 + sq * 8) = av;
    __syncthreads();

    short8 af[2];
    #pragma unroll
    for (int mf = 0; mf < 2; ++mf)
      af[mf] = *(const short8*)(As + (wm * 32 + mf * 16 + lrow) * 40 + kq * 8);
    #pragma unroll
    for (int nf = 0; nf < 4; ++nf) {
      const int ncol = n0 + wn * 64 + nf * 16 + lrow;
      short8 bfv = *(const short8*)(Wtcat + ncol * 288 + k0 + kq * 8);
      acc[0][nf] = __builtin_amdgcn_mfma_f32_16x16x32_bf16(af[0], bfv, acc[0][nf], 0, 0, 0);
      acc[1][nf] = __builtin_amdgcn_mfma_f32_16x16x32_bf16(af[1], bfv, acc[1][nf], 0, 0, 0);
    }
    __syncthreads();
  }

  #pragma unroll
  for (int mf = 0; mf < 2; ++mf)
    #pragma unroll
    for (int nf = 0; nf < 4; ++nf) {
      const int nglob = n0 + wn * 64 + nf * 16 + lrow;
      #pragma unroll
      for (int r = 0; r < 4; ++r) {
        const int m = bm0 + wm * 32 + mf * 16 + kq * 4 + r;
        if (m < NNODES) {
          float v = acc[mf][nf][r];
          if (nglob < 256) {
            float h = v + nb1[nglob];
            h1_node[m * 256 + nglob] = f2bf(h > 0.f ? h : 0.f);
          } else {
            const int pc = nglob - 256;           // Pall column
            float vv = v;
            if (pc < 256)       vv += tb1[pc];    // type-MLP src projection
            else if (pc >= 512) vv += db1[pc - 512]; // dir-MLP src projection
            Pall[m * 1024 + pc] = f2bf(vv);
          }
        }
      }
    }
}

// ---------------- K2: node tail 256 -> 128(relu) -> 119 ----------------
__global__ __launch_bounds__(256) void k2_node_tail(
    const short* __restrict__ h1_node, const short* __restrict__ Wt2cat,
    const short* __restrict__ Wt3n, const float* __restrict__ nb2,
    const float* __restrict__ nb3, float* __restrict__ out_node)
{
  __shared__ short h2s[64 * 136];
  const int t = threadIdx.x;
  const int bm0 = blockIdx.x * 64;
  const int wid = t >> 6, lane = t & 63;
  const int wm = wid >> 1, wn = wid & 1;
  const int lrow = lane & 15, kq = lane >> 4;

  f4 acc[2][4];
  #pragma unroll
  for (int a = 0; a < 2; ++a)
    #pragma unroll
    for (int b = 0; b < 4; ++b) acc[a][b] = (f4){0.f, 0.f, 0.f, 0.f};

  #pragma unroll
  for (int kc = 0; kc < 8; ++kc) {
    short8 af[2];
    #pragma unroll
    for (int mf = 0; mf < 2; ++mf) {
      const int m = bm0 + wm * 32 + mf * 16 + lrow;
      if (m < NNODES) af[mf] = *(const short8*)(h1_node + m * 256 + kc * 32 + kq * 8);
      else            af[mf] = (short8){0, 0, 0, 0, 0, 0, 0, 0};
    }
    #pragma unroll
    for (int nf = 0; nf < 4; ++nf) {
      const int ncol = wn * 64 + nf * 16 + lrow;
      short8 bfv = *(const short8*)(Wt2cat + ncol * 256 + kc * 32 + kq * 8);
      acc[0][nf] = __builtin_amdgcn_mfma_f32_16x16x32_bf16(af[0], bfv, acc[0][nf], 0, 0, 0);
      acc[1][nf] = __builtin_amdgcn_mfma_f32_16x16x32_bf16(af[1], bfv, acc[1][nf], 0, 0, 0);
    }
  }
  #pragma unroll
  for (int mf = 0; mf < 2; ++mf)
    #pragma unroll
    for (int nf = 0; nf < 4; ++nf) {
      const int n = wn * 64 + nf * 16 + lrow;
      #pragma unroll
      for (int r = 0; r < 4; ++r) {
        const int ml = wm * 32 + mf * 16 + kq * 4 + r;
        float h = acc[mf][nf][r] + nb2[n];
        h2s[ml * 136 + n] = f2bf(h > 0.f ? h : 0.f);
      }
    }
  __syncthreads();

  f4 acc2[2][4];
  #pragma unroll
  for (int a = 0; a < 2; ++a)
    #pragma unroll
    for (int b = 0; b < 4; ++b) acc2[a][b] = (f4){0.f, 0.f, 0.f, 0.f};

  #pragma unroll
  for (int kc = 0; kc < 4; ++kc) {
    short8 af[2];
    #pragma unroll
    for (int mf = 0; mf < 2; ++mf)
      af[mf] = *(const short8*)(h2s + (wm * 32 + mf * 16 + lrow) * 136 + kc * 32 + kq * 8);
    #pragma unroll
    for (int nf = 0; nf < 4; ++nf) {
      const int ncol = wn * 64 + nf * 16 + lrow;
      short8 bfv = *(const short8*)(Wt3n + ncol * 128 + kc * 32 + kq * 8);
      acc2[0][nf] = __builtin_amdgcn_mfma_f32_16x16x32_bf16(af[0], bfv, acc2[0][nf], 0, 0, 0);
      acc2[1][nf] = __builtin_amdgcn_mfma_f32_16x16x32_bf16(af[1], bfv, acc2[1][nf], 0, 0, 0);
    }
  }
  #pragma unroll
  for (int mf = 0; mf < 2; ++mf)
    #pragma unroll
    for (int nf = 0; nf < 4; ++nf) {
      const int n = wn * 64 + nf * 16 + lrow;
      #pragma unroll
      for (int r = 0; r < 4; ++r) {
        const int m = bm0 + wm * 32 + mf * 16 + kq * 4 + r;
        if (m < NNODES && n < NT) out_node[m * NT + n] = acc2[mf][nf][r] + nb3[n];
      }
    }
}

// ---------------- K3: edge tail, barrier-free, one wave = 16 edges ----------------
// Per wave: private LDS slice (16x264 bf16, h2 aliased at offset 0). No __syncthreads.
// Biases b1 are pre-folded into Pall by k1, so gather is pure add+relu.
__global__ __launch_bounds__(256, 4) void k3_edge(
    const short* __restrict__ Pall, const int* __restrict__ eidx,
    const short* __restrict__ Wt2cat, const short* __restrict__ Wt3t, const short* __restrict__ Wt3d,
    const float* __restrict__ tb2, const float* __restrict__ tb3,
    const float* __restrict__ db2, const float* __restrict__ db3,
    float* __restrict__ out_t, float* __restrict__ out_d)
{
  __shared__ short lds[4 * 16 * 264];          // 33,792 B -> 4 blocks/CU
  const int t = threadIdx.x;
  const int wid = t >> 6, lane = t & 63;
  short* wlds = lds + wid * (16 * 264);        // wave-private slice
  const int e0w = blockIdx.x * 64 + wid * 16;  // NEDGES = 6250*64 exactly
  const int r = lane >> 2, q = lane & 3;       // gather coords: row 0..15, quarter 0..3
  const int lrow = lane & 15, kq = lane >> 4;  // mfma lane coords

  const int s_idx = eidx[e0w + r];
  const int d_idx = eidx[NEDGES + e0w + r];

  #pragma unroll 1
  for (int ph = 0; ph < 2; ++ph) {
    const float* b2 = ph ? db2 : tb2;
    const float* b3 = ph ? db3 : tb3;
    const short* W3 = ph ? Wt3d : Wt3t;
    const int poff1 = ph ? 512 : 0;
    const int poff2 = ph ? 768 : 256;
    const int w2row0 = 128 + ph * 128;

    // ---- gather + add + relu -> h1 (wave-private LDS) ----
    {
      const short* Ps = Pall + (long)s_idx * 1024 + poff1 + q * 64;
      const short* Pd = Pall + (long)d_idx * 1024 + poff2 + q * 64;
      short8 v1[8], v2[8];
      #pragma unroll
      for (int c = 0; c < 8; ++c) v1[c] = *(const short8*)(Ps + c * 8);
      #pragma unroll
      for (int c = 0; c < 8; ++c) v2[c] = *(const short8*)(Pd + c * 8);
      #pragma unroll
      for (int c = 0; c < 8; ++c) {
        short8 o;
        #pragma unroll
        for (int x = 0; x < 8; ++x) {
          float f = bf2f(v1[c][x]) + bf2f(v2[c][x]);
          o[x] = f2bf(f > 0.f ? f : 0.f);
        }
        *(short8*)(wlds + r * 264 + q * 64 + c * 8) = o;
      }
    }
    // same-wave DS ordering: writes above precede reads below in the DS pipe

    // ---- layer 2: h1[16x256] @ W2[256x128] -> acc ----
    f4 acc[8];
    #pragma unroll
    for (int nf = 0; nf < 8; ++nf) acc[nf] = (f4){0.f, 0.f, 0.f, 0.f};
    #pragma unroll
    for (int kc = 0; kc < 8; ++kc) {
      short8 af = *(const short8*)(wlds + lrow * 264 + kc * 32 + kq * 8);
      #pragma unroll
      for (int nf = 0; nf < 8; ++nf) {
        short8 bfv = *(const short8*)(Wt2cat + (w2row0 + nf * 16 + lrow) * 256 + kc * 32 + kq * 8);
        acc[nf] = __builtin_amdgcn_mfma_f32_16x16x32_bf16(af, bfv, acc[nf], 0, 0, 0);
      }
    }

    // ---- h2 = relu(acc + b2) -> LDS (aliased over h1 region, offset 0) ----
    #pragma unroll
    for (int nf = 0; nf < 8; ++nf) {
      const int n2 = nf * 16 + lrow;
      const float bb = b2[n2];
      #pragma unroll
      for (int rr = 0; rr < 4; ++rr) {
        float h = acc[nf][rr] + bb;
        wlds[(kq * 4 + rr) * 136 + n2] = f2bf(h > 0.f ? h : 0.f);
      }
    }

    // ---- layer 3: tiny N, dot products (4 lanes per edge) ----
    {
      const int el = lane >> 2, n = lane & 3;
      const int ncols = ph ? 3 : 4;
      float s = 0.f;
      #pragma unroll
      for (int kk = 0; kk < 16; ++kk) {
        short8 hv = *(const short8*)(wlds + el * 136 + kk * 8);
        short8 wv = *(const short8*)(W3 + n * 128 + kk * 8);  // W3 buffers are 1024B, n=3 read is in-bounds
        #pragma unroll
        for (int x = 0; x < 8; ++x) s += bf2f(hv[x]) * bf2f(wv[x]);
      }
      if (n < ncols) {
        if (ph == 0) out_t[(e0w + el) * 4 + n] = s + b3[n];
        else         out_d[(e0w + el) * 3 + n] = s + b3[n];
      }
    }
  }
}

extern "C" void kernel_launch(void* const* d_in, const int* in_sizes, int n_in,
                              void* d_out, int out_size, void* d_ws, size_t ws_size,
                              hipStream_t stream)
{
  const float* lat = (const float*)d_in[0];
  const float* pos = (const float*)d_in[1];
  const int* batch = (const int*)d_in[2];
  const int* eidx  = (const int*)d_in[3];
  const float* nW1 = (const float*)d_in[4];  const float* nb1 = (const float*)d_in[5];
  const float* nW2 = (const float*)d_in[6];  const float* nb2 = (const float*)d_in[7];
  const float* nW3 = (const float*)d_in[8];  const float* nb3 = (const float*)d_in[9];
  const float* tW1 = (const float*)d_in[10]; const float* tb1 = (const float*)d_in[11];
  const float* tW2 = (const float*)d_in[12]; const float* tb2 = (const float*)d_in[13];
  const float* tW3 = (const float*)d_in[14]; const float* tb3 = (const float*)d_in[15];
  const float* dW1 = (const float*)d_in[16]; const float* db1 = (const float*)d_in[17];
  const float* dW2 = (const float*)d_in[18]; const float* db2 = (const float*)d_in[19];
  const float* dW3 = (const float*)d_in[20]; const float* db3 = (const float*)d_in[21];

  char* ws = (char*)d_ws;
  short* latent_bf = (short*)(ws + 0);          //   1,048,576 B
  short* pos_bf    = (short*)(ws + 1048576);    //   1,600,000 B
  short* Wtcat     = (short*)(ws + 2648576);    //     737,280 B
  short* Wt2cat    = (short*)(ws + 3385856);    //     196,608 B
  short* Wt3n      = (short*)(ws + 3582464);    //      32,768 B
  short* Wt3t      = (short*)(ws + 3615232);    //       1,024 B
  short* Wt3d      = (short*)(ws + 3616256);    //       1,024 B (768 used)
  short* h1_node   = (short*)(ws + 3617280);    //  51,200,000 B
  short* Pall      = (short*)(ws + 54817280);   // 204,800,000 B  -> total ~259.6 MB

  float* out_node = (float*)d_out;
  float* out_t = out_node + (size_t)NNODES * NT;
  float* out_d = out_t + (size_t)NEDGES * 4;

  prep_kernel<<<7065, 256, 0, stream>>>(lat, pos, nW1, tW1, dW1, nW2, tW2, dW2,
                                        nW3, tW3, dW3, latent_bf, pos_bf, Wtcat,
                                        Wt2cat, Wt3n, Wt3t, Wt3d);
  k1_gemm<<<dim3(1563, 10), 256, 0, stream>>>(latent_bf, pos_bf, batch, Wtcat,
                                              nb1, tb1, db1, h1_node, Pall);
  k2_node_tail<<<1563, 256, 0, stream>>>(h1_node, Wt2cat, Wt3n, nb2, nb3, out_node);
  k3_edge<<<6250, 256, 0, stream>>>(Pall, eidx, Wt2cat, Wt3t, Wt3d,
                                    tb2, tb3, db2, db3, out_t, out_d);
}

// Round 3
// 636.115 us; speedup vs baseline: 1.3720x; 1.3720x over previous
//
#include <hip/hip_runtime.h>
#include <hip/hip_bf16.h>
#include <stdint.h>

#define LATF 256
#define NT 119
#define NNODES 100000
#define NEDGES 400000

typedef __attribute__((ext_vector_type(8))) short short8;
typedef __attribute__((ext_vector_type(4))) float f4;

__device__ __forceinline__ float bf2f(short u) {
  union { uint32_t i; float f; } v; v.i = ((uint32_t)(uint16_t)u) << 16; return v.f;
}
__device__ __forceinline__ short f2bf(float f) {
  union { float f; uint32_t i; } v; v.f = f;
  uint32_t r = (v.i + 0x7fffu + ((v.i >> 16) & 1u)) >> 16;
  return (short)(uint16_t)r;
}

// ---------------- prep: cast + build transposed weight layouts ----------------
__global__ __launch_bounds__(256) void prep_kernel(
    const float* __restrict__ lat, const float* __restrict__ pos,
    const float* __restrict__ nW1, const float* __restrict__ tW1, const float* __restrict__ dW1,
    const float* __restrict__ nW2, const float* __restrict__ tW2, const float* __restrict__ dW2,
    const float* __restrict__ nW3, const float* __restrict__ tW3, const float* __restrict__ dW3,
    short* __restrict__ latent_bf, short* __restrict__ pos_bf,
    short* __restrict__ Wtcat, short* __restrict__ Wt2cat,
    short* __restrict__ Wt3n, short* __restrict__ Wt3t, short* __restrict__ Wt3d)
{
  int i = blockIdx.x * 256 + threadIdx.x;
  if (i < 524288) { latent_bf[i] = f2bf(lat[i]); return; }
  i -= 524288;
  if (i < 800000) { pos_bf[i] = f2bf(pos[i]); return; }
  i -= 800000;
  if (i < 1280 * 288) {               // Wtcat[n][k], n-major, K padded 264->288
    int n = i / 288, k = i % 288;
    float v = 0.f;
    if (k < 264) {
      if (n < 256)       v = nW1[k * 256 + n];
      else if (n < 512)  v = tW1[k * 256 + (n - 256)];
      else if (n < 768)  v = tW1[(264 + k) * 256 + (n - 512)];
      else if (n < 1024) v = dW1[k * 256 + (n - 768)];
      else               v = dW1[(264 + k) * 256 + (n - 1024)];
    }
    Wtcat[n * 288 + k] = f2bf(v);
    return;
  }
  i -= 1280 * 288;
  if (i < 384 * 256) {                // Wt2cat[n][k]: rows 0-127 nW2, 128-255 tW2, 256-383 dW2
    int n = i / 256, k = i % 256;
    float v = (n < 128) ? nW2[k * 128 + n] : (n < 256) ? tW2[k * 128 + (n - 128)]
                                                       : dW2[k * 128 + (n - 256)];
    Wt2cat[n * 256 + k] = f2bf(v);
    return;
  }
  i -= 384 * 256;
  if (i < 128 * 128) {                // Wt3n[n][k], n padded 119->128
    int n = i / 128, k = i % 128;
    Wt3n[i] = (n < NT) ? f2bf(nW3[k * NT + n]) : (short)0;
    return;
  }
  i -= 128 * 128;
  if (i < 4 * 128) { int n = i / 128, k = i % 128; Wt3t[i] = f2bf(tW3[k * 4 + n]); return; }
  i -= 512;
  if (i < 3 * 128) { int n = i / 128, k = i % 128; Wt3d[i] = f2bf(dW3[k * 3 + n]); return; }
}

// ---------------- K1: nodeFeat x [nW1 | tW1_src | tW1_dst | dW1_src | dW1_dst] ----------------
// M=100000, K=288 (pad), N=1280. BM=64, BN=128, 4 waves (2x2), each wave 32x64.
// Epilogue writes Pall in k3's layout: [t_src | d_src | t_dst | d_dst], with
// tb1 folded into t_src and db1 folded into d_src.
__global__ __launch_bounds__(256) void k1_gemm(
    const short* __restrict__ latent_bf, const short* __restrict__ pos_bf,
    const int* __restrict__ batch, const short* __restrict__ Wtcat,
    const float* __restrict__ nb1, const float* __restrict__ tb1, const float* __restrict__ db1,
    short* __restrict__ h1_node, short* __restrict__ Pall)
{
  __shared__ short As[64 * 40];   // 32 K-elems + pad 8 -> row stride 80B (2-way max)
  const int t = threadIdx.x;
  const int bm0 = blockIdx.x * 64;
  const int n0 = blockIdx.y * 128;
  const int wid = t >> 6, lane = t & 63;
  const int wm = wid >> 1, wn = wid & 1;
  const int lrow = lane & 15, kq = lane >> 4;

  const int sr = t >> 2, sq = t & 3;          // staging: 4 threads per row
  const int m_stage = bm0 + sr;
  const bool svalid = (m_stage < NNODES);
  const int g = svalid ? batch[m_stage] : 0;

  f4 acc[2][4];
  #pragma unroll
  for (int a = 0; a < 2; ++a)
    #pragma unroll
    for (int b = 0; b < 4; ++b) acc[a][b] = (f4){0.f, 0.f, 0.f, 0.f};

  for (int kc = 0; kc < 9; ++kc) {
    const int k0 = kc * 32;
    short8 av = {0, 0, 0, 0, 0, 0, 0, 0};
    if (svalid) {
      if (k0 < 256)      av = *(const short8*)(latent_bf + g * 256 + k0 + sq * 8);
      else if (sq == 0)  av = *(const short8*)(pos_bf + m_stage * 8);
    }
    *(short8*)(As + sr * 40 + sq * 8) = av;
    __syncthreads();

    short8 af[2];
    #pragma unroll
    for (int mf = 0; mf < 2; ++mf)
      af[mf] = *(const short8*)(As + (wm * 32 + mf * 16 + lrow) * 40 + kq * 8);
    #pragma unroll
    for (int nf = 0; nf < 4; ++nf) {
      const int ncol = n0 + wn * 64 + nf * 16 + lrow;
      short8 bfv = *(const short8*)(Wtcat + ncol * 288 + k0 + kq * 8);
      acc[0][nf] = __builtin_amdgcn_mfma_f32_16x16x32_bf16(af[0], bfv, acc[0][nf], 0, 0, 0);
      acc[1][nf] = __builtin_amdgcn_mfma_f32_16x16x32_bf16(af[1], bfv, acc[1][nf], 0, 0, 0);
    }
    __syncthreads();
  }

  #pragma unroll
  for (int mf = 0; mf < 2; ++mf)
    #pragma unroll
    for (int nf = 0; nf < 4; ++nf) {
      const int nglob = n0 + wn * 64 + nf * 16 + lrow;
      #pragma unroll
      for (int r = 0; r < 4; ++r) {
        const int m = bm0 + wm * 32 + mf * 16 + kq * 4 + r;
        if (m < NNODES) {
          float v = acc[mf][nf][r];
          if (nglob < 256) {
            float h = v + nb1[nglob];
            h1_node[m * 256 + nglob] = f2bf(h > 0.f ? h : 0.f);
          } else {
            // old column order: [t_src | t_dst | d_src | d_dst]
            const int pc = nglob - 256;
            float vv = v;
            int newc = pc;
            if (pc < 256)       { vv += tb1[pc]; }               // t_src -> 0:256
            else if (pc < 512)  { newc = pc + 256; }             // t_dst -> 512:768
            else if (pc < 768)  { vv += db1[pc - 512]; newc = pc - 256; } // d_src -> 256:512
            /* else d_dst stays at 768:1024 */
            Pall[m * 1024 + newc] = f2bf(vv);
          }
        }
      }
    }
}

// ---------------- K2: node tail 256 -> 128(relu) -> 119 ----------------
__global__ __launch_bounds__(256) void k2_node_tail(
    const short* __restrict__ h1_node, const short* __restrict__ Wt2cat,
    const short* __restrict__ Wt3n, const float* __restrict__ nb2,
    const float* __restrict__ nb3, float* __restrict__ out_node)
{
  __shared__ short h2s[64 * 136];
  const int t = threadIdx.x;
  const int bm0 = blockIdx.x * 64;
  const int wid = t >> 6, lane = t & 63;
  const int wm = wid >> 1, wn = wid & 1;
  const int lrow = lane & 15, kq = lane >> 4;

  f4 acc[2][4];
  #pragma unroll
  for (int a = 0; a < 2; ++a)
    #pragma unroll
    for (int b = 0; b < 4; ++b) acc[a][b] = (f4){0.f, 0.f, 0.f, 0.f};

  #pragma unroll
  for (int kc = 0; kc < 8; ++kc) {
    short8 af[2];
    #pragma unroll
    for (int mf = 0; mf < 2; ++mf) {
      const int m = bm0 + wm * 32 + mf * 16 + lrow;
      if (m < NNODES) af[mf] = *(const short8*)(h1_node + m * 256 + kc * 32 + kq * 8);
      else            af[mf] = (short8){0, 0, 0, 0, 0, 0, 0, 0};
    }
    #pragma unroll
    for (int nf = 0; nf < 4; ++nf) {
      const int ncol = wn * 64 + nf * 16 + lrow;
      short8 bfv = *(const short8*)(Wt2cat + ncol * 256 + kc * 32 + kq * 8);
      acc[0][nf] = __builtin_amdgcn_mfma_f32_16x16x32_bf16(af[0], bfv, acc[0][nf], 0, 0, 0);
      acc[1][nf] = __builtin_amdgcn_mfma_f32_16x16x32_bf16(af[1], bfv, acc[1][nf], 0, 0, 0);
    }
  }
  #pragma unroll
  for (int mf = 0; mf < 2; ++mf)
    #pragma unroll
    for (int nf = 0; nf < 4; ++nf) {
      const int n = wn * 64 + nf * 16 + lrow;
      #pragma unroll
      for (int r = 0; r < 4; ++r) {
        const int ml = wm * 32 + mf * 16 + kq * 4 + r;
        float h = acc[mf][nf][r] + nb2[n];
        h2s[ml * 136 + n] = f2bf(h > 0.f ? h : 0.f);
      }
    }
  __syncthreads();

  f4 acc2[2][4];
  #pragma unroll
  for (int a = 0; a < 2; ++a)
    #pragma unroll
    for (int b = 0; b < 4; ++b) acc2[a][b] = (f4){0.f, 0.f, 0.f, 0.f};

  #pragma unroll
  for (int kc = 0; kc < 4; ++kc) {
    short8 af[2];
    #pragma unroll
    for (int mf = 0; mf < 2; ++mf)
      af[mf] = *(const short8*)(h2s + (wm * 32 + mf * 16 + lrow) * 136 + kc * 32 + kq * 8);
    #pragma unroll
    for (int nf = 0; nf < 4; ++nf) {
      const int ncol = wn * 64 + nf * 16 + lrow;
      short8 bfv = *(const short8*)(Wt3n + ncol * 128 + kc * 32 + kq * 8);
      acc2[0][nf] = __builtin_amdgcn_mfma_f32_16x16x32_bf16(af[0], bfv, acc2[0][nf], 0, 0, 0);
      acc2[1][nf] = __builtin_amdgcn_mfma_f32_16x16x32_bf16(af[1], bfv, acc2[1][nf], 0, 0, 0);
    }
  }
  #pragma unroll
  for (int mf = 0; mf < 2; ++mf)
    #pragma unroll
    for (int nf = 0; nf < 4; ++nf) {
      const int n = wn * 64 + nf * 16 + lrow;
      #pragma unroll
      for (int r = 0; r < 4; ++r) {
        const int m = bm0 + wm * 32 + mf * 16 + kq * 4 + r;
        if (m < NNODES && n < NT) out_node[m * NT + n] = acc2[mf][nf][r] + nb3[n];
      }
    }
}

// ---------------- K3: edge tail, single combined gather session ----------------
// Pall layout: [t_src(0:256) | d_src(256:512) | t_dst(512:768) | d_dst(768:1024)].
// Per edge: src cols 0:512 (1KB contiguous) + dst cols 512:1024 (1KB contiguous).
// h1[32][512] covers type-h1 (cols 0:256) and dir-h1 (256:512) for both GEMMs.
// h2 aliased over dead h1 halves: h2_t -> cols 0:128, h2_d -> cols 128:256.
__global__ __launch_bounds__(256) void k3_edge(
    const short* __restrict__ Pall, const int* __restrict__ eidx,
    const short* __restrict__ Wt2cat, const short* __restrict__ Wt3t, const short* __restrict__ Wt3d,
    const float* __restrict__ tb2, const float* __restrict__ tb3,
    const float* __restrict__ db2, const float* __restrict__ db3,
    float* __restrict__ out_t, float* __restrict__ out_d)
{
  __shared__ short h1[32 * 520];               // 33,280 B -> 4 blocks/CU
  const int t = threadIdx.x;
  const int wid = t >> 6, lane = t & 63;
  const int e0 = blockIdx.x * 32;              // NEDGES = 12500*32 exactly
  const int er = t >> 3, j = t & 7;            // gather: 8 lanes per edge
  const int lrow = lane & 15, kq = lane >> 4;  // mfma lane coords

  const int s_idx = eidx[e0 + er];
  const int d_idx = eidx[NEDGES + e0 + er];

  // ---- gather both phases: 8 lanes/edge, per-instr 8 contiguous 128B lines ----
  {
    const short* Ps = Pall + (long)s_idx * 1024 + j * 8;
    const short* Pd = Pall + (long)d_idx * 1024 + 512 + j * 8;
    short8 sv[8], dv[8];
    #pragma unroll
    for (int c = 0; c < 8; ++c) sv[c] = *(const short8*)(Ps + c * 64);
    #pragma unroll
    for (int c = 0; c < 8; ++c) dv[c] = *(const short8*)(Pd + c * 64);
    #pragma unroll
    for (int c = 0; c < 8; ++c) {
      short8 o;
      #pragma unroll
      for (int x = 0; x < 8; ++x) {
        float f = bf2f(sv[c][x]) + bf2f(dv[c][x]);
        o[x] = f2bf(f > 0.f ? f : 0.f);
      }
      *(short8*)(h1 + er * 520 + c * 64 + j * 8) = o;
    }
  }
  __syncthreads();

  // ---- layer2 TYPE: h1[:,0:256] @ tW2 (Wt2cat rows 128:256). M=32, wave owns 32 N-cols.
  f4 acc_t[2][2];
  #pragma unroll
  for (int a = 0; a < 2; ++a)
    #pragma unroll
    for (int b = 0; b < 2; ++b) acc_t[a][b] = (f4){0.f, 0.f, 0.f, 0.f};
  #pragma unroll
  for (int kc = 0; kc < 8; ++kc) {
    short8 a0 = *(const short8*)(h1 + lrow * 520 + kc * 32 + kq * 8);
    short8 a1 = *(const short8*)(h1 + (16 + lrow) * 520 + kc * 32 + kq * 8);
    #pragma unroll
    for (int nf = 0; nf < 2; ++nf) {
      short8 bfv = *(const short8*)(Wt2cat + (128 + wid * 32 + nf * 16 + lrow) * 256 + kc * 32 + kq * 8);
      acc_t[0][nf] = __builtin_amdgcn_mfma_f32_16x16x32_bf16(a0, bfv, acc_t[0][nf], 0, 0, 0);
      acc_t[1][nf] = __builtin_amdgcn_mfma_f32_16x16x32_bf16(a1, bfv, acc_t[1][nf], 0, 0, 0);
    }
  }
  __syncthreads();   // all waves done reading h1_t before overwrite

  // ---- h2_t = relu(acc_t + tb2) -> cols 0:128 (over dead h1_t) ----
  #pragma unroll
  for (int mf = 0; mf < 2; ++mf)
    #pragma unroll
    for (int nf = 0; nf < 2; ++nf) {
      const int n2 = wid * 32 + nf * 16 + lrow;
      const float bb = tb2[n2];
      #pragma unroll
      for (int rr = 0; rr < 4; ++rr) {
        float h = acc_t[mf][nf][rr] + bb;
        h1[(mf * 16 + kq * 4 + rr) * 520 + n2] = f2bf(h > 0.f ? h : 0.f);
      }
    }

  // ---- layer2 DIR: h1[:,256:512] @ dW2 (Wt2cat rows 256:384) ----
  f4 acc_d[2][2];
  #pragma unroll
  for (int a = 0; a < 2; ++a)
    #pragma unroll
    for (int b = 0; b < 2; ++b) acc_d[a][b] = (f4){0.f, 0.f, 0.f, 0.f};
  #pragma unroll
  for (int kc = 0; kc < 8; ++kc) {
    short8 a0 = *(const short8*)(h1 + lrow * 520 + 256 + kc * 32 + kq * 8);
    short8 a1 = *(const short8*)(h1 + (16 + lrow) * 520 + 256 + kc * 32 + kq * 8);
    #pragma unroll
    for (int nf = 0; nf < 2; ++nf) {
      short8 bfv = *(const short8*)(Wt2cat + (256 + wid * 32 + nf * 16 + lrow) * 256 + kc * 32 + kq * 8);
      acc_d[0][nf] = __builtin_amdgcn_mfma_f32_16x16x32_bf16(a0, bfv, acc_d[0][nf], 0, 0, 0);
      acc_d[1][nf] = __builtin_amdgcn_mfma_f32_16x16x32_bf16(a1, bfv, acc_d[1][nf], 0, 0, 0);
    }
  }

  // ---- h2_d = relu(acc_d + db2) -> cols 128:256 (over dead h1_t upper half) ----
  #pragma unroll
  for (int mf = 0; mf < 2; ++mf)
    #pragma unroll
    for (int nf = 0; nf < 2; ++nf) {
      const int n2 = wid * 32 + nf * 16 + lrow;
      const float bb = db2[n2];
      #pragma unroll
      for (int rr = 0; rr < 4; ++rr) {
        float h = acc_d[mf][nf][rr] + bb;
        h1[(mf * 16 + kq * 4 + rr) * 520 + 128 + n2] = f2bf(h > 0.f ? h : 0.f);
      }
    }
  __syncthreads();

  // ---- layer 3: 8 threads/edge, n=0..3 type, n=4..6 dir ----
  {
    const int e2 = t >> 3, n = t & 7;
    if (n < 7) {
      const bool isT = (n < 4);
      const int col = isT ? n : n - 4;
      const short* W3 = isT ? (Wt3t + col * 128) : (Wt3d + col * 128);
      const int base = e2 * 520 + (isT ? 0 : 128);
      float s = 0.f;
      #pragma unroll
      for (int kk = 0; kk < 16; ++kk) {
        short8 hv = *(const short8*)(h1 + base + kk * 8);
        short8 wv = *(const short8*)(W3 + kk * 8);
        #pragma unroll
        for (int x = 0; x < 8; ++x) s += bf2f(hv[x]) * bf2f(wv[x]);
      }
      if (isT) out_t[(e0 + e2) * 4 + col] = s + tb3[col];
      else     out_d[(e0 + e2) * 3 + col] = s + db3[col];
    }
  }
}

extern "C" void kernel_launch(void* const* d_in, const int* in_sizes, int n_in,
                              void* d_out, int out_size, void* d_ws, size_t ws_size,
                              hipStream_t stream)
{
  const float* lat = (const float*)d_in[0];
  const float* pos = (const float*)d_in[1];
  const int* batch = (const int*)d_in[2];
  const int* eidx  = (const int*)d_in[3];
  const float* nW1 = (const float*)d_in[4];  const float* nb1 = (const float*)d_in[5];
  const float* nW2 = (const float*)d_in[6];  const float* nb2 = (const float*)d_in[7];
  const float* nW3 = (const float*)d_in[8];  const float* nb3 = (const float*)d_in[9];
  const float* tW1 = (const float*)d_in[10]; const float* tb1 = (const float*)d_in[11];
  const float* tW2 = (const float*)d_in[12]; const float* tb2 = (const float*)d_in[13];
  const float* tW3 = (const float*)d_in[14]; const float* tb3 = (const float*)d_in[15];
  const float* dW1 = (const float*)d_in[16]; const float* db1 = (const float*)d_in[17];
  const float* dW2 = (const float*)d_in[18]; const float* db2 = (const float*)d_in[19];
  const float* dW3 = (const float*)d_in[20]; const float* db3 = (const float*)d_in[21];

  char* ws = (char*)d_ws;
  short* latent_bf = (short*)(ws + 0);          //   1,048,576 B
  short* pos_bf    = (short*)(ws + 1048576);    //   1,600,000 B
  short* Wtcat     = (short*)(ws + 2648576);    //     737,280 B
  short* Wt2cat    = (short*)(ws + 3385856);    //     196,608 B
  short* Wt3n      = (short*)(ws + 3582464);    //      32,768 B
  short* Wt3t      = (short*)(ws + 3615232);    //       1,024 B
  short* Wt3d      = (short*)(ws + 3616256);    //       1,024 B (768 used)
  short* h1_node   = (short*)(ws + 3617280);    //  51,200,000 B
  short* Pall      = (short*)(ws + 54817280);   // 204,800,000 B  -> total ~259.6 MB

  float* out_node = (float*)d_out;
  float* out_t = out_node + (size_t)NNODES * NT;
  float* out_d = out_t + (size_t)NEDGES * 4;

  prep_kernel<<<7065, 256, 0, stream>>>(lat, pos, nW1, tW1, dW1, nW2, tW2, dW2,
                                        nW3, tW3, dW3, latent_bf, pos_bf, Wtcat,
                                        Wt2cat, Wt3n, Wt3t, Wt3d);
  k1_gemm<<<dim3(1563, 10), 256, 0, stream>>>(latent_bf, pos_bf, batch, Wtcat,
                                              nb1, tb1, db1, h1_node, Pall);
  k2_node_tail<<<1563, 256, 0, stream>>>(h1_node, Wt2cat, Wt3n, nb2, nb3, out_node);
  k3_edge<<<12500, 256, 0, stream>>>(Pall, eidx, Wt2cat, Wt3t, Wt3d,
                                     tb2, tb3, db2, db3, out_t, out_d);
}